// Round 18
// baseline (102.800 us; speedup 1.0000x reference)
//
#include <hip/hip_runtime.h>
#include <hip/hip_bf16.h>

// HeteroLinear fused forward on gfx950: out[i] = x[i] @ W[tv[i]] + b[tv[i]]
// N=131072, IN=OUT=256, T=8, tv sorted. HBM floor ~256 MB -> ~41 us.
// R18: uniform x-stream + 2x TLP via 1024-thread blocks.
// Diagnosis: all col-split variants bunch a wave's cold x-loads into its
// first col-pass (~25-50% of compute) -> HBM duty ~60% (measured). Fix:
// wave = 16 rows x FULL 256 cols (acc[16]=64 VGPR, x touched exactly once,
// cold loads uniform across all 8 ks-steps) and 16 waves/block = 4
// waves/SIMD (2x all prior rounds). W[t] 128 KB LDS staged once per pass
// (proven src-side XOR-swizzle DMA); ONE barrier per pass; dist-2 raw
// f32x4 x-ring (proven). Pressure ~112 < 128 cap (1024-thr hard cap).

#define NROWS 131072
#define KD 256
#define ND 256
#define BM 256                      // rows per block
#define NBLK (NROWS / BM)           // 512

typedef __attribute__((ext_vector_type(8))) short short8;
typedef __attribute__((ext_vector_type(4))) float f32x4;
typedef __attribute__((ext_vector_type(4))) float flt4;

typedef __attribute__((address_space(3))) unsigned int lds_u32_t;
typedef __attribute__((address_space(1))) unsigned int glb_u32_t;

__device__ inline unsigned short f2bf(float f) {
    unsigned int u = __float_as_uint(f);
    u += 0x7FFFu + ((u >> 16) & 1u);   // RNE
    return (unsigned short)(u >> 16);
}

// ---- weight prep: wT[t][n][k] = bf16(w[t][k][n]) ----
__global__ __launch_bounds__(256) void prep_weights(const float* __restrict__ w,
                                                    unsigned short* __restrict__ wT) {
    __shared__ unsigned short L[8][264];
    const int t  = blockIdx.x >> 5;
    const int k0 = (blockIdx.x & 31) * 8;
    const int tid = threadIdx.x;

    #pragma unroll
    for (int i = 0; i < 2; ++i) {
        int idx = i * 256 + tid;
        int kr  = idx >> 6;
        int nq  = idx & 63;
        const flt4* src = (const flt4*)(w + ((size_t)t * 256 + k0 + kr) * 256);
        flt4 v = src[nq];
        #pragma unroll
        for (int j = 0; j < 4; ++j) L[kr][nq * 4 + j] = f2bf(v[j]);
    }
    __syncthreads();

    int n = tid;
    short8 v;
    #pragma unroll
    for (int j = 0; j < 8; ++j) v[j] = (short)L[j][n];
    *(short8*)(wT + ((size_t)t * 256 + n) * 256 + k0) = v;
}

// ---- main GEMM: 1024 threads, 16 waves x (16 rows x 256 cols) ----
__global__ __launch_bounds__(1024) void hetero_gemm(
        const float* __restrict__ x, const int* __restrict__ tv,
        const unsigned short* __restrict__ wT, const float* __restrict__ bias,
        float* __restrict__ out) {
    // W[t] tile, bf16, [col][k], 512 B per col, XOR-swizzled 16B chunks:
    // LDS chunk c of col holds global k-chunk c ^ (col&7).
    __shared__ short Bs[ND * KD];            // 128 KiB

    const int tid  = threadIdx.x;
    const int lane = tid & 63;
    const int wv   = tid >> 6;               // 16 waves
    const int cl   = lane & 15;
    const int kg   = lane >> 4;
    const int r0   = blockIdx.x * BM;
    const int rw   = r0 + wv * 16;           // wave's 16-row strip

    const int tmin = tv[r0];
    const int tmax = tv[r0 + BM - 1];
    const int ty   = tv[rw + cl];            // this lane's row type
    const int s    = cl & 7;                 // swizzle key (col&7 == cl&7)

    // per-lane x row pointer (row rw+cl), k-offset kg*8
    const float* xr = x + (size_t)(rw + cl) * KD + kg * 8;

    for (int t = tmin; t <= tmax; ++t) {
        if (t > tmin) __syncthreads();       // prev-pass reads done before overwrite

        // ---- stage W[t] -> LDS: 8192 16B chunks, 8 rounds of 1024 ----
        {
            const unsigned short* Wt = wT + (size_t)t * (KD * ND);
            #pragma unroll
            for (int rnd = 0; rnd < 8; ++rnd) {
                int i   = rnd * 1024 + tid;  // chunk index 0..8191 (per-lane)
                int col = i >> 5;
                int c   = i & 31;
                int sc  = c ^ (col & 7);     // source-side swizzle
                const unsigned short* gp = Wt + col * KD + sc * 8;
                __builtin_amdgcn_global_load_lds(
                    (const glb_u32_t*)gp,
                    (lds_u32_t*)((char*)Bs + (size_t)(rnd * 1024 + wv * 64) * 16),
                    16, 0, 0);
            }
        }
        __syncthreads();                     // drain DMA; tile ready

        // ---- compute: full 256 cols, x touched exactly once, uniform ----
        f32x4 zero = {0.f, 0.f, 0.f, 0.f};
        f32x4 acc[16];
        #pragma unroll
        for (int n = 0; n < 16; ++n) acc[n] = zero;

        // dist-2 raw prefetch: two 2x-f32x4 buffers, consume-then-reissue
        f32x4 xbA[2], xbB[2];
        xbA[0] = *(const f32x4*)(xr);           // ks=0
        xbA[1] = *(const f32x4*)(xr + 4);
        xbB[0] = *(const f32x4*)(xr + 32);      // ks=1
        xbB[1] = *(const f32x4*)(xr + 36);

        auto step = [&](f32x4 (&xb)[2], int ks) {
            short8 a;
            #pragma unroll
            for (int j = 0; j < 4; ++j) {
                a[j]     = (short)f2bf(xb[0][j]);
                a[4 + j] = (short)f2bf(xb[1][j]);
            }
            if (ks + 2 < 8) {                // reissue freed buffer for ks+2
                xb[0] = *(const f32x4*)(xr + (ks + 2) * 32);
                xb[1] = *(const f32x4*)(xr + (ks + 2) * 32 + 4);
            }
            #pragma unroll
            for (int n = 0; n < 16; ++n) {
                int lc = n * 16 + cl;                 // col
                int kc = ((ks << 2) | kg) ^ s;        // swizzled 16B chunk
                short8 b = *(const short8*)((char*)Bs + (size_t)lc * 512 + (kc << 4));
                // swapped operands: D[w-col][x-row]
                acc[n] = __builtin_amdgcn_mfma_f32_16x16x32_bf16(b, a, acc[n], 0, 0, 0);
            }
        };
        step(xbA, 0); step(xbB, 1); step(xbA, 2); step(xbB, 3);
        step(xbA, 4); step(xbB, 5); step(xbA, 6); step(xbB, 7);

        // ---- epilogue: lane owns row rw+cl, cols n*16+kg*4..+3 ----
        if (ty == t) {
            float* orow = out + (size_t)(rw + cl) * ND + kg * 4;
            #pragma unroll
            for (int n = 0; n < 16; ++n) {
                f32x4 bv = *(const f32x4*)(bias + (size_t)t * ND + n * 16 + kg * 4);
                *(f32x4*)(orow + n * 16) = acc[n] + bv;
            }
        }
    }
}

extern "C" void kernel_launch(void* const* d_in, const int* in_sizes, int n_in,
                              void* d_out, int out_size, void* d_ws, size_t ws_size,
                              hipStream_t stream) {
    const float* x    = (const float*)d_in[0];
    const int*   tv   = (const int*)d_in[1];
    const float* w    = (const float*)d_in[2];
    const float* bias = (const float*)d_in[3];
    float* out = (float*)d_out;
    unsigned short* wT = (unsigned short*)d_ws;   // 8*256*256*2 = 1 MiB

    prep_weights<<<dim3(256), dim3(256), 0, stream>>>(w, wT);
    hetero_gemm<<<dim3(NBLK), dim3(1024), 0, stream>>>(x, tv, wT, bias, out);
}

// Round 19
// 89.717 us; speedup vs baseline: 1.1458x; 1.1458x over previous
//
#include <hip/hip_runtime.h>
#include <hip/hip_bf16.h>

// HeteroLinear fused forward on gfx950: out[i] = x[i] @ W[tv[i]] + b[tv[i]]
// N=131072, IN=OUT=256, T=8, tv sorted. HBM floor ~256 MB -> ~41 us.
// R19 = R18's uniform-x-stream wave shape at a LEGAL register budget.
// R18's 1024-thr block hit the 64-VGPR hard cap (acc[16]=64 alone) ->
// spill (WRITE 188 MB) and the theory went untested. Cap table (measured):
// 256thr=free, 512thr=128, 1024thr=64. So: 512-thr block, 8 waves x
// (16 rows x FULL 256 cols). x touched exactly once per pass, cold loads
// uniform across all 8 ks-steps (no col-pass bunching). acc[16]=64 +
// ring 16 + frags/addr ~32 = ~112 <= 128. W[t] 128 KB LDS staged once per
// pass (proven swizzled DMA), ONE barrier per pass, dist-2 raw f32x4 ring.

#define NROWS 131072
#define KD 256
#define ND 256
#define BM 128                      // rows per block (8 waves x 16)
#define NBLK (NROWS / BM)           // 1024

typedef __attribute__((ext_vector_type(8))) short short8;
typedef __attribute__((ext_vector_type(4))) float f32x4;
typedef __attribute__((ext_vector_type(4))) float flt4;

typedef __attribute__((address_space(3))) unsigned int lds_u32_t;
typedef __attribute__((address_space(1))) unsigned int glb_u32_t;

__device__ inline unsigned short f2bf(float f) {
    unsigned int u = __float_as_uint(f);
    u += 0x7FFFu + ((u >> 16) & 1u);   // RNE
    return (unsigned short)(u >> 16);
}

// ---- weight prep: wT[t][n][k] = bf16(w[t][k][n]) ----
__global__ __launch_bounds__(256) void prep_weights(const float* __restrict__ w,
                                                    unsigned short* __restrict__ wT) {
    __shared__ unsigned short L[8][264];
    const int t  = blockIdx.x >> 5;
    const int k0 = (blockIdx.x & 31) * 8;
    const int tid = threadIdx.x;

    #pragma unroll
    for (int i = 0; i < 2; ++i) {
        int idx = i * 256 + tid;
        int kr  = idx >> 6;
        int nq  = idx & 63;
        const flt4* src = (const flt4*)(w + ((size_t)t * 256 + k0 + kr) * 256);
        flt4 v = src[nq];
        #pragma unroll
        for (int j = 0; j < 4; ++j) L[kr][nq * 4 + j] = f2bf(v[j]);
    }
    __syncthreads();

    int n = tid;
    short8 v;
    #pragma unroll
    for (int j = 0; j < 8; ++j) v[j] = (short)L[j][n];
    *(short8*)(wT + ((size_t)t * 256 + n) * 256 + k0) = v;
}

// ---- main GEMM: 512 threads, 8 waves x (16 rows x 256 cols) ----
__global__ __launch_bounds__(512) void hetero_gemm(
        const float* __restrict__ x, const int* __restrict__ tv,
        const unsigned short* __restrict__ wT, const float* __restrict__ bias,
        float* __restrict__ out) {
    // W[t] tile, bf16, [col][k], 512 B per col, XOR-swizzled 16B chunks:
    // LDS chunk c of col holds global k-chunk c ^ (col&7).
    __shared__ short Bs[ND * KD];            // 128 KiB

    const int tid  = threadIdx.x;
    const int lane = tid & 63;
    const int wv   = tid >> 6;               // 8 waves
    const int cl   = lane & 15;
    const int kg   = lane >> 4;
    const int r0   = blockIdx.x * BM;
    const int rw   = r0 + wv * 16;           // wave's 16-row strip

    const int tmin = tv[r0];
    const int tmax = tv[r0 + BM - 1];
    const int ty   = tv[rw + cl];            // this lane's row type
    const int s    = cl & 7;                 // swizzle key (col&7 == cl&7)

    // per-lane x row pointer (row rw+cl), k-offset kg*8
    const float* xr = x + (size_t)(rw + cl) * KD + kg * 8;

    for (int t = tmin; t <= tmax; ++t) {
        if (t > tmin) __syncthreads();       // prev-pass reads done before overwrite

        // ---- stage W[t] -> LDS: 8192 16B chunks, 16 rounds of 512 ----
        {
            const unsigned short* Wt = wT + (size_t)t * (KD * ND);
            #pragma unroll
            for (int rnd = 0; rnd < 16; ++rnd) {
                int i   = rnd * 512 + tid;   // chunk index 0..8191 (per-lane)
                int col = i >> 5;
                int c   = i & 31;
                int sc  = c ^ (col & 7);     // source-side swizzle
                const unsigned short* gp = Wt + col * KD + sc * 8;
                __builtin_amdgcn_global_load_lds(
                    (const glb_u32_t*)gp,
                    (lds_u32_t*)((char*)Bs + (size_t)(rnd * 512 + wv * 64) * 16),
                    16, 0, 0);
            }
        }
        __syncthreads();                     // drain DMA; tile ready

        // ---- compute: full 256 cols, x touched exactly once, uniform ----
        f32x4 zero = {0.f, 0.f, 0.f, 0.f};
        f32x4 acc[16];
        #pragma unroll
        for (int n = 0; n < 16; ++n) acc[n] = zero;

        // dist-2 raw prefetch: two 2x-f32x4 buffers, consume-then-reissue
        f32x4 xbA[2], xbB[2];
        xbA[0] = *(const f32x4*)(xr);           // ks=0
        xbA[1] = *(const f32x4*)(xr + 4);
        xbB[0] = *(const f32x4*)(xr + 32);      // ks=1
        xbB[1] = *(const f32x4*)(xr + 36);

        auto step = [&](f32x4 (&xb)[2], int ks) {
            short8 a;
            #pragma unroll
            for (int j = 0; j < 4; ++j) {
                a[j]     = (short)f2bf(xb[0][j]);
                a[4 + j] = (short)f2bf(xb[1][j]);
            }
            if (ks + 2 < 8) {                // reissue freed buffer for ks+2
                xb[0] = *(const f32x4*)(xr + (ks + 2) * 32);
                xb[1] = *(const f32x4*)(xr + (ks + 2) * 32 + 4);
            }
            #pragma unroll
            for (int n = 0; n < 16; ++n) {
                int lc = n * 16 + cl;                 // col
                int kc = ((ks << 2) | kg) ^ s;        // swizzled 16B chunk
                short8 b = *(const short8*)((char*)Bs + (size_t)lc * 512 + (kc << 4));
                // swapped operands: D[w-col][x-row]
                acc[n] = __builtin_amdgcn_mfma_f32_16x16x32_bf16(b, a, acc[n], 0, 0, 0);
            }
        };
        step(xbA, 0); step(xbB, 1); step(xbA, 2); step(xbB, 3);
        step(xbA, 4); step(xbB, 5); step(xbA, 6); step(xbB, 7);

        // ---- epilogue: lane owns row rw+cl, cols n*16+kg*4..+3 ----
        if (ty == t) {
            float* orow = out + (size_t)(rw + cl) * ND + kg * 4;
            #pragma unroll
            for (int n = 0; n < 16; ++n) {
                f32x4 bv = *(const f32x4*)(bias + (size_t)t * ND + n * 16 + kg * 4);
                *(f32x4*)(orow + n * 16) = acc[n] + bv;
            }
        }
    }
}

extern "C" void kernel_launch(void* const* d_in, const int* in_sizes, int n_in,
                              void* d_out, int out_size, void* d_ws, size_t ws_size,
                              hipStream_t stream) {
    const float* x    = (const float*)d_in[0];
    const int*   tv   = (const int*)d_in[1];
    const float* w    = (const float*)d_in[2];
    const float* bias = (const float*)d_in[3];
    float* out = (float*)d_out;
    unsigned short* wT = (unsigned short*)d_ws;   // 8*256*256*2 = 1 MiB

    prep_weights<<<dim3(256), dim3(256), 0, stream>>>(w, wT);
    hetero_gemm<<<dim3(NBLK), dim3(512), 0, stream>>>(x, tv, wT, bias, out);
}

// Round 20
// 70.711 us; speedup vs baseline: 1.4538x; 1.2688x over previous
//
#include <hip/hip_runtime.h>
#include <hip/hip_bf16.h>

// HeteroLinear fused forward on gfx950: out[i] = x[i] @ W[tv[i]] + b[tv[i]]
// N=131072, IN=OUT=256, T=8, tv sorted. HBM floor ~200-256 MB -> ~41 us.
// R20 = R13 (best, 66.8 us) made PERSISTENT over 2 tiles:
//  - grid 256 blocks (1/CU exactly), each owns 512 rows = 2 x 256-row tiles
//  - W[t] staged ONLY on type change (tv sorted, ~16K-row runs -> ~97% of
//    blocks stage once and run both tiles barrier-free); stage guarded by
//    one pre-barrier + one post-drain barrier
//  - compute per tile verbatim R13: two col-halves, acc[2][8], dist-2 raw
//    f32x4 x-ring, swizzled ds_read_b128 from the 128 KB W-tile,
//    swapped-operand MFMA, plain f32x4 stores
// Proven levers only: fewer barriers, fewer stages, pipeline continuity.

#define NROWS 131072
#define KD 256
#define ND 256
#define TM 256                      // rows per tile
#define TPB 2                       // tiles per block
#define BM (TM * TPB)               // 512 rows per block
#define NBLK (NROWS / BM)           // 256 = 1 block/CU

typedef __attribute__((ext_vector_type(8))) short short8;
typedef __attribute__((ext_vector_type(4))) float f32x4;
typedef __attribute__((ext_vector_type(4))) float flt4;

typedef __attribute__((address_space(3))) unsigned int lds_u32_t;
typedef __attribute__((address_space(1))) unsigned int glb_u32_t;

__device__ inline unsigned short f2bf(float f) {
    unsigned int u = __float_as_uint(f);
    u += 0x7FFFu + ((u >> 16) & 1u);   // RNE
    return (unsigned short)(u >> 16);
}

// ---- weight prep: wT[t][n][k] = bf16(w[t][k][n]) ----
__global__ __launch_bounds__(256) void prep_weights(const float* __restrict__ w,
                                                    unsigned short* __restrict__ wT) {
    __shared__ unsigned short L[8][264];
    const int t  = blockIdx.x >> 5;
    const int k0 = (blockIdx.x & 31) * 8;
    const int tid = threadIdx.x;

    #pragma unroll
    for (int i = 0; i < 2; ++i) {
        int idx = i * 256 + tid;
        int kr  = idx >> 6;
        int nq  = idx & 63;
        const flt4* src = (const flt4*)(w + ((size_t)t * 256 + k0 + kr) * 256);
        flt4 v = src[nq];
        #pragma unroll
        for (int j = 0; j < 4; ++j) L[kr][nq * 4 + j] = f2bf(v[j]);
    }
    __syncthreads();

    int n = tid;
    short8 v;
    #pragma unroll
    for (int j = 0; j < 8; ++j) v[j] = (short)L[j][n];
    *(short8*)(wT + ((size_t)t * 256 + n) * 256 + k0) = v;
}

// ---- main GEMM: persistent 2-tile blocks ----
__global__ __launch_bounds__(512) void hetero_gemm(
        const float* __restrict__ x, const int* __restrict__ tv,
        const unsigned short* __restrict__ wT, const float* __restrict__ bias,
        float* __restrict__ out) {
    // W[t] tile, bf16, [col][k], 512 B per col, XOR-swizzled 16B chunks:
    // LDS chunk c of col holds global k-chunk c ^ (col&7).
    __shared__ short Bs[ND * KD];            // 128 KiB

    const int tid  = threadIdx.x;
    const int lane = tid & 63;
    const int wv   = tid >> 6;               // 8 waves
    const int cl   = lane & 15;
    const int kg   = lane >> 4;
    const int r0a  = blockIdx.x * BM;
    const int s    = cl & 7;                 // swizzle key (col&7 == cl&7)

    int staged_t = -1;

    #pragma unroll
    for (int tile = 0; tile < TPB; ++tile) {
        const int r0 = r0a + tile * TM;
        const int rw = r0 + wv * 32;         // wave's 32-row strip

        const int tmin = tv[r0];
        const int tmax = tv[r0 + TM - 1];
        const int ty0  = tv[rw + cl];        // type of row (m=0)
        const int ty1  = tv[rw + 16 + cl];   // type of row (m=1)

        // per-lane x row pointers (rows rw+m*16+cl), k-offset kg*8
        const float* xr0 = x + (size_t)(rw + cl) * KD + kg * 8;
        const float* xr1 = x + (size_t)(rw + 16 + cl) * KD + kg * 8;

        for (int t = tmin; t <= tmax; ++t) {
            if (t != staged_t) {             // ~once per block (tv sorted)
                __syncthreads();             // prior reads of Bs complete
                const unsigned short* Wt = wT + (size_t)t * (KD * ND);
                #pragma unroll
                for (int rnd = 0; rnd < 16; ++rnd) {
                    int i   = rnd * 512 + tid;   // chunk index 0..8191
                    int col = i >> 5;
                    int c   = i & 31;
                    int sc  = c ^ (col & 7);     // source-side swizzle
                    const unsigned short* gp = Wt + col * KD + sc * 8;
                    __builtin_amdgcn_global_load_lds(
                        (const glb_u32_t*)gp,
                        (lds_u32_t*)((char*)Bs + (size_t)(rnd * 512 + wv * 64) * 16),
                        16, 0, 0);
                }
                __syncthreads();             // drain DMA; tile ready
                staged_t = t;
            }

            // ---- compute in two col-halves: acc 64 VGPR per half ----
            #pragma unroll
            for (int half = 0; half < 2; ++half) {
                const int c0 = half * 128;

                f32x4 zero = {0.f, 0.f, 0.f, 0.f};
                f32x4 acc[2][8];
                #pragma unroll
                for (int m = 0; m < 2; ++m)
                    #pragma unroll
                    for (int n = 0; n < 8; ++n) acc[m][n] = zero;

                // dist-2 raw prefetch: two 4x-f32x4 buffers
                f32x4 xbA[4], xbB[4];
                xbA[0] = *(const f32x4*)(xr0);          // ks=0
                xbA[1] = *(const f32x4*)(xr0 + 4);
                xbA[2] = *(const f32x4*)(xr1);
                xbA[3] = *(const f32x4*)(xr1 + 4);
                xbB[0] = *(const f32x4*)(xr0 + 32);     // ks=1
                xbB[1] = *(const f32x4*)(xr0 + 36);
                xbB[2] = *(const f32x4*)(xr1 + 32);
                xbB[3] = *(const f32x4*)(xr1 + 36);

                auto step = [&](f32x4 (&xb)[4], int ks) {
                    short8 a[2];
                    #pragma unroll
                    for (int m = 0; m < 2; ++m) {
                        #pragma unroll
                        for (int j = 0; j < 4; ++j) {
                            a[m][j]     = (short)f2bf(xb[2 * m][j]);
                            a[m][4 + j] = (short)f2bf(xb[2 * m + 1][j]);
                        }
                    }
                    if (ks + 2 < 8) {        // reissue freed buffer for ks+2
                        xb[0] = *(const f32x4*)(xr0 + (ks + 2) * 32);
                        xb[1] = *(const f32x4*)(xr0 + (ks + 2) * 32 + 4);
                        xb[2] = *(const f32x4*)(xr1 + (ks + 2) * 32);
                        xb[3] = *(const f32x4*)(xr1 + (ks + 2) * 32 + 4);
                    }
                    #pragma unroll
                    for (int n = 0; n < 8; ++n) {
                        int lc = c0 + n * 16 + cl;            // col
                        int kc = ((ks << 2) | kg) ^ s;        // swizzled chunk
                        short8 b = *(const short8*)((char*)Bs + (size_t)lc * 512 + (kc << 4));
                        // swapped operands: D[w-col][x-row]
                        acc[0][n] = __builtin_amdgcn_mfma_f32_16x16x32_bf16(b, a[0], acc[0][n], 0, 0, 0);
                        acc[1][n] = __builtin_amdgcn_mfma_f32_16x16x32_bf16(b, a[1], acc[1][n], 0, 0, 0);
                    }
                };
                step(xbA, 0); step(xbB, 1); step(xbA, 2); step(xbB, 3);
                step(xbA, 4); step(xbB, 5); step(xbA, 6); step(xbB, 7);

                // ---- epilogue: rows rw+m*16+cl, cols c0+n*16+kg*4 ----
                #pragma unroll
                for (int m = 0; m < 2; ++m) {
                    int tym = (m == 0) ? ty0 : ty1;
                    if (tym == t) {
                        float* orow = out + (size_t)(rw + m * 16 + cl) * ND + c0 + kg * 4;
                        #pragma unroll
                        for (int n = 0; n < 8; ++n) {
                            f32x4 bv = *(const f32x4*)(bias + (size_t)t * ND + c0 + n * 16 + kg * 4);
                            *(f32x4*)(orow + n * 16) = acc[m][n] + bv;
                        }
                    }
                }
            }
        }
    }
}

extern "C" void kernel_launch(void* const* d_in, const int* in_sizes, int n_in,
                              void* d_out, int out_size, void* d_ws, size_t ws_size,
                              hipStream_t stream) {
    const float* x    = (const float*)d_in[0];
    const int*   tv   = (const int*)d_in[1];
    const float* w    = (const float*)d_in[2];
    const float* bias = (const float*)d_in[3];
    float* out = (float*)d_out;
    unsigned short* wT = (unsigned short*)d_ws;   // 8*256*256*2 = 1 MiB

    prep_weights<<<dim3(256), dim3(256), 0, stream>>>(w, wT);
    hetero_gemm<<<dim3(NBLK), dim3(512), 0, stream>>>(x, tv, wT, bias, out);
}

// Round 21
// 66.475 us; speedup vs baseline: 1.5464x; 1.0637x over previous
//
#include <hip/hip_runtime.h>
#include <hip/hip_bf16.h>

// HeteroLinear fused forward on gfx950: out[i] = x[i] @ W[tv[i]] + b[tv[i]]
// N=131072, IN=OUT=256, T=8, tv sorted. HBM floor ~200-256 MB -> ~41 us.
// R21 = R13 (best, 66.8 us) + ONE micro-fix: cross-half ring wrap.
// Mechanism: vmcnt retires IN-ORDER (m135). R13 issues each half's 16
// epilogue stores, then the next half's 8 prologue loads; the compiler's
// wait for those loads therefore waits for ALL stores to retire
// (~300-500 cy, twice per pass, fully exposed). Fix: the dist-2 ring's
// reissue WRAPS at the half boundary -- during half0's ks=6/7 the freed
// buffers reload ks=0/1 (same addresses, same A-data, L1-hit), entering
// the vmcnt queue BEFORE the stores. Half1's first MFMA then waits only
// on loads. Everything else verbatim R13.

#define NROWS 131072
#define KD 256
#define ND 256
#define BM 256                      // rows per block
#define NBLK (NROWS / BM)           // 512

typedef __attribute__((ext_vector_type(8))) short short8;
typedef __attribute__((ext_vector_type(4))) float f32x4;
typedef __attribute__((ext_vector_type(4))) float flt4;

typedef __attribute__((address_space(3))) unsigned int lds_u32_t;
typedef __attribute__((address_space(1))) unsigned int glb_u32_t;

__device__ inline unsigned short f2bf(float f) {
    unsigned int u = __float_as_uint(f);
    u += 0x7FFFu + ((u >> 16) & 1u);   // RNE
    return (unsigned short)(u >> 16);
}

// ---- weight prep: wT[t][n][k] = bf16(w[t][k][n]) ----
__global__ __launch_bounds__(256) void prep_weights(const float* __restrict__ w,
                                                    unsigned short* __restrict__ wT) {
    __shared__ unsigned short L[8][264];
    const int t  = blockIdx.x >> 5;
    const int k0 = (blockIdx.x & 31) * 8;
    const int tid = threadIdx.x;

    #pragma unroll
    for (int i = 0; i < 2; ++i) {
        int idx = i * 256 + tid;
        int kr  = idx >> 6;
        int nq  = idx & 63;
        const flt4* src = (const flt4*)(w + ((size_t)t * 256 + k0 + kr) * 256);
        flt4 v = src[nq];
        #pragma unroll
        for (int j = 0; j < 4; ++j) L[kr][nq * 4 + j] = f2bf(v[j]);
    }
    __syncthreads();

    int n = tid;
    short8 v;
    #pragma unroll
    for (int j = 0; j < 8; ++j) v[j] = (short)L[j][n];
    *(short8*)(wT + ((size_t)t * 256 + n) * 256 + k0) = v;
}

// ---- main GEMM ----
__global__ __launch_bounds__(512) void hetero_gemm(
        const float* __restrict__ x, const int* __restrict__ tv,
        const unsigned short* __restrict__ wT, const float* __restrict__ bias,
        float* __restrict__ out) {
    // W[t] tile, bf16, [col][k], 512 B per col-row, XOR-swizzled 16B chunks:
    // LDS chunk c of col holds global k-chunk c ^ (col&7).
    __shared__ short Bs[BM * KD];            // 128 KiB

    const int tid  = threadIdx.x;
    const int lane = tid & 63;
    const int wv   = tid >> 6;               // 8 waves
    const int cl   = lane & 15;
    const int kg   = lane >> 4;
    const int r0   = blockIdx.x * BM;
    const int rw   = r0 + wv * 32;           // wave's 32-row strip

    const int tmin = tv[r0];
    const int tmax = tv[r0 + BM - 1];
    const int ty0  = tv[rw + cl];            // type of row (m=0)
    const int ty1  = tv[rw + 16 + cl];       // type of row (m=1)
    const int s    = cl & 7;                 // swizzle key (col&7 == cl&7)

    // per-lane x row pointers (rows rw+m*16+cl), k-offset kg*8
    const float* xr0 = x + (size_t)(rw + cl) * KD + kg * 8;
    const float* xr1 = x + (size_t)(rw + 16 + cl) * KD + kg * 8;

    for (int t = tmin; t <= tmax; ++t) {
        if (t > tmin) __syncthreads();       // prev-pass reads done before overwrite

        // ---- stage W[t] -> LDS: 8192 16B chunks, 16 wave-rounds ----
        {
            const unsigned short* Wt = wT + (size_t)t * (KD * ND);
            #pragma unroll
            for (int rnd = 0; rnd < 16; ++rnd) {
                int i   = rnd * 512 + tid;   // chunk index 0..8191 (per-lane)
                int col = i >> 5;
                int c   = i & 31;
                int sc  = c ^ (col & 7);     // source-side swizzle
                const unsigned short* gp = Wt + col * KD + sc * 8;
                __builtin_amdgcn_global_load_lds(
                    (const glb_u32_t*)gp,
                    (lds_u32_t*)((char*)Bs + (size_t)(rnd * 512 + wv * 64) * 16),
                    16, 0, 0);
            }
        }
        __syncthreads();                     // drain DMA; tile ready

        // ---- prime the dist-2 ring once per pass (ks=0, ks=1) ----
        f32x4 xbA[4], xbB[4];
        xbA[0] = *(const f32x4*)(xr0);
        xbA[1] = *(const f32x4*)(xr0 + 4);
        xbA[2] = *(const f32x4*)(xr1);
        xbA[3] = *(const f32x4*)(xr1 + 4);
        xbB[0] = *(const f32x4*)(xr0 + 32);
        xbB[1] = *(const f32x4*)(xr0 + 36);
        xbB[2] = *(const f32x4*)(xr1 + 32);
        xbB[3] = *(const f32x4*)(xr1 + 36);

        // ---- compute in two col-halves: acc 64 VGPR per half ----
        #pragma unroll
        for (int half = 0; half < 2; ++half) {
            const int c0 = half * 128;

            f32x4 zero = {0.f, 0.f, 0.f, 0.f};
            f32x4 acc[2][8];
            #pragma unroll
            for (int m = 0; m < 2; ++m)
                #pragma unroll
                for (int n = 0; n < 8; ++n) acc[m][n] = zero;

            auto step = [&](f32x4 (&xb)[4], int ks) {
                short8 a[2];
                #pragma unroll
                for (int m = 0; m < 2; ++m) {
                    #pragma unroll
                    for (int j = 0; j < 4; ++j) {
                        a[m][j]     = (short)f2bf(xb[2 * m][j]);
                        a[m][4 + j] = (short)f2bf(xb[2 * m + 1][j]);
                    }
                }
                // cross-half ring wrap: half0's ks=6/7 reload ks=0/1 (same
                // addresses, L1-hit) so half1's operands enter the vmcnt
                // queue BEFORE half0's epilogue stores (in-order retirement).
                const int nks = ks + 2;
                if (nks < 8 || half == 0) {
                    const int rk = nks & 7;
                    xb[0] = *(const f32x4*)(xr0 + rk * 32);
                    xb[1] = *(const f32x4*)(xr0 + rk * 32 + 4);
                    xb[2] = *(const f32x4*)(xr1 + rk * 32);
                    xb[3] = *(const f32x4*)(xr1 + rk * 32 + 4);
                }
                #pragma unroll
                for (int n = 0; n < 8; ++n) {
                    int lc = c0 + n * 16 + cl;            // col
                    int kc = ((ks << 2) | kg) ^ s;        // swizzled 16B chunk
                    short8 b = *(const short8*)((char*)Bs + (size_t)lc * 512 + (kc << 4));
                    // swapped operands: D[w-col][x-row]
                    acc[0][n] = __builtin_amdgcn_mfma_f32_16x16x32_bf16(b, a[0], acc[0][n], 0, 0, 0);
                    acc[1][n] = __builtin_amdgcn_mfma_f32_16x16x32_bf16(b, a[1], acc[1][n], 0, 0, 0);
                }
            };
            step(xbA, 0); step(xbB, 1); step(xbA, 2); step(xbB, 3);
            step(xbA, 4); step(xbB, 5); step(xbA, 6); step(xbB, 7);

            // ---- epilogue: rows rw+m*16+cl, cols c0+n*16+kg*4 (plain stores) ----
            #pragma unroll
            for (int m = 0; m < 2; ++m) {
                int tym = (m == 0) ? ty0 : ty1;
                if (tym == t) {
                    float* orow = out + (size_t)(rw + m * 16 + cl) * ND + c0 + kg * 4;
                    #pragma unroll
                    for (int n = 0; n < 8; ++n) {
                        f32x4 bv = *(const f32x4*)(bias + (size_t)t * ND + c0 + n * 16 + kg * 4);
                        *(f32x4*)(orow + n * 16) = acc[m][n] + bv;
                    }
                }
            }
        }
    }
}

extern "C" void kernel_launch(void* const* d_in, const int* in_sizes, int n_in,
                              void* d_out, int out_size, void* d_ws, size_t ws_size,
                              hipStream_t stream) {
    const float* x    = (const float*)d_in[0];
    const int*   tv   = (const int*)d_in[1];
    const float* w    = (const float*)d_in[2];
    const float* bias = (const float*)d_in[3];
    float* out = (float*)d_out;
    unsigned short* wT = (unsigned short*)d_ws;   // 8*256*256*2 = 1 MiB

    prep_weights<<<dim3(256), dim3(256), 0, stream>>>(w, wT);
    hetero_gemm<<<dim3(NBLK), dim3(512), 0, stream>>>(x, tv, wT, bias, out);
}